// Round 9
// baseline (421.322 us; speedup 1.0000x reference)
//
#include <hip/hip_runtime.h>
#include <hip/hip_bf16.h>
#include <hip/hip_fp16.h>
#include <cstdint>
#include <cstddef>
#include <type_traits>

// Problem constants (from reference): N=50000, E=800000, IN=512, HID=256, MID=128, OUT=64
// NOTE: edge packing below assumes N < 65536 (src index fits 16 bits). N=50000 -> ok.
#define F_IN  512
#define F_HID 256
#define F_MID 128
#define F_OUT 64

typedef __attribute__((ext_vector_type(8))) short short8;   // 8 x bf16 (4 VGPRs)
typedef __attribute__((ext_vector_type(4))) float floatx4;  // MFMA accumulator

static __device__ __forceinline__ ushort f2b(float f) {
  union { float f; unsigned u; } v; v.f = f;
  unsigned r = v.u + 0x7fffu + ((v.u >> 16) & 1u);  // round-to-nearest-even
  return (ushort)(r >> 16);
}
static __device__ __forceinline__ float blo(unsigned u) {
  union { unsigned x; float f; } v; v.x = u << 16; return v.f;
}
static __device__ __forceinline__ float bhi(unsigned u) {
  union { unsigned x; float f; } v; v.x = u & 0xffff0000u; return v.f;
}
// 8x f32 -> 8x bf16 via packed v_cvt_pk_bf16_f32 (RNE)
static __device__ __forceinline__ short8 cvt8(float4 lo, float4 hi) {
  union { __hip_bfloat162 h[4]; short8 s; } r;
  r.h[0] = __float22bfloat162_rn({lo.x, lo.y});
  r.h[1] = __float22bfloat162_rn({lo.z, lo.w});
  r.h[2] = __float22bfloat162_rn({hi.x, hi.y});
  r.h[3] = __float22bfloat162_rn({hi.z, hi.w});
  return r.s;
}

// async global->LDS DMA, 16B per lane. LDS dest must be WAVE-UNIFORM base; HW scatters
// lane i to base + i*16. Global src is per-lane. size must be a literal (16).
static __device__ __forceinline__ void gload_lds16(const void* gsrc, void* ldst) {
  __builtin_amdgcn_global_load_lds(
      (const __attribute__((address_space(1))) unsigned int*)gsrc,
      (__attribute__((address_space(3))) unsigned int*)ldst, 16, 0, 0);
}

// counted waitcnt: wait until <=N VMEM outstanding (+ drain LDS queue for x-wave visibility).
// NEVER 0 in the ring main loop -- that is the whole point (T4).
template<int N> static __device__ __forceinline__ void vm_wait() {
  asm volatile("s_waitcnt vmcnt(%0) lgkmcnt(0)" :: "n"(N) : "memory");
}

// ---------------- CSR build ----------------

__global__ __launch_bounds__(256) void hist_kernel(const int* __restrict__ dst,
                                                   int* __restrict__ cnt, int e) {
  int i = blockIdx.x * 256 + threadIdx.x;
  if (i < e) atomicAdd(&cnt[dst[i]], 1);
}

__global__ __launch_bounds__(1024) void scan1_kernel(int* __restrict__ cnt,
                                                     int* __restrict__ rp,
                                                     int* __restrict__ part,
                                                     float* __restrict__ dinv, int n) {
  __shared__ int buf[1024];
  int tid = threadIdx.x;
  int i = blockIdx.x * 1024 + tid;
  int v = (i < n) ? cnt[i] : 0;
  buf[tid] = v;
  __syncthreads();
  for (int off = 1; off < 1024; off <<= 1) {
    int t = (tid >= off) ? buf[tid - off] : 0;
    __syncthreads();
    buf[tid] += t;
    __syncthreads();
  }
  if (i < n) {
    rp[i] = buf[tid] - v;
    cnt[i] = 0;
    dinv[i] = rsqrtf(1.0f + (float)v);  // deg includes self-loop
  }
  if (tid == 1023) part[blockIdx.x] = buf[1023];
}

__global__ __launch_bounds__(1024) void scan2_kernel(int* __restrict__ part,
                                                     int* __restrict__ rp, int nb, int n) {
  __shared__ int buf[1024];
  int tid = threadIdx.x;
  int v = (tid < nb) ? part[tid] : 0;
  buf[tid] = v;
  __syncthreads();
  for (int off = 1; off < 1024; off <<= 1) {
    int t = (tid >= off) ? buf[tid - off] : 0;
    __syncthreads();
    buf[tid] += t;
    __syncthreads();
  }
  if (tid < nb) part[tid] = buf[tid] - v;
  if (tid == nb - 1) rp[n] = buf[tid];
}

__global__ __launch_bounds__(1024) void scan3_kernel(const int* __restrict__ part,
                                                     int* __restrict__ rp, int n) {
  int b = blockIdx.x;
  int i = b * 1024 + threadIdx.x;
  if (b > 0 && i < n) rp[i] += part[b];
}

// fill CSR adjacency; packs src (low 16 bits) + f16 edge weight (high 16 bits).
__global__ __launch_bounds__(256) void fill_kernel(const int* __restrict__ src,
                                                   const int* __restrict__ dst,
                                                   const int* __restrict__ rp,
                                                   int* __restrict__ cur,
                                                   const float* __restrict__ dinv,
                                                   unsigned* __restrict__ edg, int e) {
  int i = blockIdx.x * 256 + threadIdx.x;
  if (i < e) {
    int s = src[i], d = dst[i];
    int p = rp[d] + atomicAdd(&cur[d], 1);
    float w = dinv[s] * dinv[d];
    edg[p] = ((unsigned)__half_as_ushort(__float2half_rn(w)) << 16) | (unsigned)s;
  }
}

// ---------------- prep: 3 weight transposes + x f32->bf16 conversion, ONE launch ----------
// items [0, xit): xb[8i..8i+7] = bf16(x[8i..8i+7])   (vectorized, xit = N*512/8 or 0)
// items beyond: scalar transposes W[K][F] -> WT[F][K] for W1, W2, Wc.
__global__ __launch_bounds__(256) void prep_kernel(const float* __restrict__ x,
                                                   ushort* __restrict__ xb, int xit,
                                                   const float* __restrict__ W1, ushort* __restrict__ w1t,
                                                   const float* __restrict__ W2, ushort* __restrict__ w2t,
                                                   const float* __restrict__ Wc, ushort* __restrict__ wct) {
  int i = blockIdx.x * 256 + threadIdx.x;
  if (i < xit) {
    const float* p = x + (size_t)i * 8;
    float4 lo = *(const float4*)p;
    float4 hi = *(const float4*)(p + 4);
    union { short8 s; uint4 u; } o; o.s = cvt8(lo, hi);
    *(uint4*)(xb + (size_t)i * 8) = o.u;
    return;
  }
  int j = i - xit;
  if (j < F_IN * F_HID) {
    int k = j / F_HID, f = j - k * F_HID;
    w1t[(size_t)f * F_IN + k] = f2b(W1[j]);
  } else if ((j -= F_IN * F_HID) < F_HID * F_MID) {
    int k = j / F_MID, f = j - k * F_MID;
    w2t[(size_t)f * F_HID + k] = f2b(W2[j]);
  } else if ((j -= F_HID * F_MID) < F_MID * F_OUT) {
    int k = j / F_OUT, f = j - k * F_OUT;
    wct[(size_t)f * F_MID + k] = f2b(Wc[j]);
  }
}

// ---------------- MFMA GEMM: 3-buffer ring, depth-2 prefetch, counted vmcnt (T3/T4) -------
// C[M,F] = A[M,K]*B[K,F]; A bf16 [M][K], BT bf16 [F][K]. Tile 64(M) x NT, BK=64.
// Round-8 diagnosis: __syncthreads' implicit vmcnt(0) gives each tile's loads only ONE
// ~130cyc MFMA window of cover vs ~300-900cyc latency; halving barrier count bought 9%.
// Ring: per iter `s_waitcnt vmcnt(L)` (L = successor tile's loads IN FLIGHT, never 0) +
// raw s_barrier. Invariant at iter-k top: only tile k+1's L ops are newer than tile k's
// -> vmcnt(L) proves tile k landed while k+1 stays in flight (2 MFMA phases of cover).
// Race audit: readers of buf[(k+2)%3]'s old content are in iter k-1, all complete before
// barrier_k, and the overwriting stage issues after barrier_k -> 1 barrier/iter suffices.
// LDS swizzle identical to round 8 (verified: SQ_LDS_BANK_CONFLICT == 0): 128B rows ->
// bank = 16B-slot only; stored[r][s]=orig[r][s^(r&7)] via pre-swizzled DMA source col;
// readers use slot^(ml&7). PAIRX: col-tile pairs 8 ids apart -> same XCD L2 (verified:
// FETCH halved). LSM: fused log_softmax epilogue. OOB rows clamped on load, guarded on store.
template<int K, int NT, bool OUT_F32, bool LSM, bool PAIRX>
__global__ __launch_bounds__(256) void gemm_ring(const ushort* __restrict__ A16,
                                                 const ushort* __restrict__ BT,
                                                 const float* __restrict__ bias,
                                                 void* __restrict__ Cv,
                                                 int M, int F) {
  constexpr int NK   = K / 64;        // K-iterations
  constexpr int NJ   = NT / 64;       // col fragments per wave
  constexpr int NCHB = NT / 32;       // 4KB B chunks per tile
  constexpr int L    = NCHB + 2;      // DMA instrs per wave per tile (B chunks + 2 A chunks)
  __shared__ ushort As[3][64 * 64];   // 3 x 8 KB
  __shared__ ushort Bs[3][NT * 64];   // 3 x (NT/8) KB
  const int tid = threadIdx.x, lane = tid & 63, wv = tid >> 6;
  const int q = lane >> 4, ml = lane & 15;

  int bx = blockIdx.x, by = blockIdx.y;
  if (PAIRX) {
    int id = bx + (int)gridDim.x * by;
    int lim = ((int)gridDim.x & ~7) * 2;
    if (id < lim) { int u = id >> 4, v = id & 15; bx = u * 8 + (v & 7); by = v >> 3; }
    else { int r = id - lim; bx = (lim >> 1) + (r >> 1); by = r & 1; }
  }
  const int bm = bx << 6, bn = by * NT;
  const int wn = wv * (NT / 4);

  const int srow = tid >> 3;                      // staging row 0..31 within a 32-row chunk
  const int scS = ((tid & 7) ^ (srow & 7)) << 3;  // pre-swizzled source col (elements)

  const ushort* a0 = A16 + (size_t)min(bm + srow, M - 1) * K + scS;
  const ushort* a1 = A16 + (size_t)min(bm + 32 + srow, M - 1) * K + scS;
  const ushort* bsrc[NCHB];
#pragma unroll
  for (int c = 0; c < NCHB; c++) {
    int rb = min(bn + 32 * c + srow, F - 1);
    bsrc[c] = BT + (size_t)rb * K + scS;
  }

  // stage one 64-K tile into ring slot `buf` (L wave-level DMA instructions)
  auto stage = [&](int buf, int k0) {
#pragma unroll
    for (int c = 0; c < NCHB; c++)
      gload_lds16(bsrc[c] + k0, (char*)&Bs[buf][0] + c * 4096 + wv * 1024);
    gload_lds16(a0 + k0, (char*)&As[buf][0] + wv * 1024);
    gload_lds16(a1 + k0, (char*)&As[buf][0] + 4096 + wv * 1024);
  };

  floatx4 acc[4][NJ] = {};

  // prologue: two tiles in flight
  stage(0, 0);
  if (NK > 1) stage(1, 64);

#pragma unroll
  for (int k = 0; k < NK; k++) {
    // tile k ready-check: the only newer VMEM is tile k+1's L ops (if it exists)
    if (k + 1 < NK) vm_wait<L>(); else vm_wait<0>();
    __builtin_amdgcn_s_barrier();                 // all waves' tile-k loads landed
    __builtin_amdgcn_sched_barrier(0);            // no motion across the sync point

    const int cur = k % 3;
    short8 af[2][4], bf[2][NJ];
#pragma unroll
    for (int kk2 = 0; kk2 < 2; kk2++) {
      const int slot = ((kk2 << 2) + q) ^ (ml & 7);
#pragma unroll
      for (int i = 0; i < 4; i++)
        af[kk2][i] = *(const short8*)((const char*)&As[cur][0] + (16 * i + ml) * 128 + slot * 16);
#pragma unroll
      for (int j = 0; j < NJ; j++)
        bf[kk2][j] = *(const short8*)((const char*)&Bs[cur][0] + (wn + 16 * j + ml) * 128 + slot * 16);
    }
#pragma unroll
    for (int kk2 = 0; kk2 < 2; kk2++)
#pragma unroll
      for (int i = 0; i < 4; i++)
#pragma unroll
        for (int j = 0; j < NJ; j++)
          acc[i][j] = __builtin_amdgcn_mfma_f32_16x16x32_bf16(af[kk2][i], bf[kk2][j], acc[i][j], 0, 0, 0);

    if (k + 2 < NK) stage((k + 2) % 3, (k + 2) * 64);  // after barrier: prev readers done
  }

  if constexpr (LSM) {
    __shared__ float lsm[64][65];   // stride 65: row-read conflict-free
    __syncthreads();                // LSM reuses no ring LDS, but order vs ring reads anyway
#pragma unroll
    for (int i = 0; i < 4; i++)
#pragma unroll
      for (int rr = 0; rr < 4; rr++)
        lsm[16 * i + q * 4 + rr][wn + ml] = acc[i][0][rr] + bias[wn + ml];
    __syncthreads();
    for (int t = 0; t < 16; ++t) {
      int r = (wv << 4) + t;
      float l = lsm[r][lane];
      float mx = l;
#pragma unroll
      for (int off = 32; off; off >>= 1) mx = fmaxf(mx, __shfl_xor(mx, off, 64));
      float e = __expf(l - mx);
#pragma unroll
      for (int off = 32; off; off >>= 1) e += __shfl_xor(e, off, 64);
      int m = bm + r;
      if (m < M) ((float*)Cv)[(size_t)m * 64 + lane] = (l - mx) - __logf(e);
    }
  } else {
    // epilogue: C/D col = lane&15, row = quad*4 + reg [m89 verified]
#pragma unroll
    for (int j = 0; j < NJ; j++) {
      int n = bn + wn + 16 * j + ml;
      float bv = bias ? bias[n] : 0.0f;
#pragma unroll
      for (int i = 0; i < 4; i++) {
#pragma unroll
        for (int rr = 0; rr < 4; rr++) {
          int m = bm + 16 * i + q * 4 + rr;
          if (m < M) {
            float val = acc[i][j][rr] + bv;
            if (OUT_F32) ((float*)Cv)[(size_t)m * F + n] = val;
            else         ((ushort*)Cv)[(size_t)m * F + n] = f2b(val);
          }
        }
      }
    }
  }
}

// ---------------- fallback gemm1 (round-8 proven): f32 A, 2-buffer, __syncthreads --------
// Used only if ws_size can't hold the bf16 copy of x. K=512, NT=128, PAIRX.
__global__ __launch_bounds__(256) void gemm1_fb(const float* __restrict__ A,
                                                const ushort* __restrict__ BT,
                                                void* __restrict__ Cv, int M, int F) {
  constexpr int K = 512, NT = 128, NJ = 2, NCHB = 4;
  __shared__ ushort As[2][64 * 64];
  __shared__ ushort Bs[2][NT * 64];
  const int tid = threadIdx.x, lane = tid & 63, wv = tid >> 6;
  const int q = lane >> 4, ml = lane & 15;

  int bx = blockIdx.x, by = blockIdx.y;
  {
    int id = bx + (int)gridDim.x * by;
    int lim = ((int)gridDim.x & ~7) * 2;
    if (id < lim) { int u = id >> 4, v = id & 15; bx = u * 8 + (v & 7); by = v >> 3; }
    else { int r = id - lim; bx = (lim >> 1) + (r >> 1); by = r & 1; }
  }
  const int bm = bx << 6, bn = by * NT;
  const int wn = wv * (NT / 4);

  const int srow = tid >> 3;
  const int slotSwz = (tid & 7) ^ (srow & 7);
  const int scS = slotSwz << 3, sc2 = (tid & 7) << 3;

  const int ra0 = min(bm + srow, M - 1), ra1 = min(bm + 32 + srow, M - 1);
  const float* a32_0 = A + (size_t)ra0 * K + sc2;
  const float* a32_1 = A + (size_t)ra1 * K + sc2;
  const ushort* bsrc[NCHB];
#pragma unroll
  for (int c = 0; c < NCHB; c++) {
    int rb = min(bn + 32 * c + srow, F - 1);
    bsrc[c] = BT + (size_t)rb * K + scS;
  }
  auto stage_lds = [&](int buf, int k0) {
#pragma unroll
    for (int c = 0; c < NCHB; c++)
      gload_lds16(bsrc[c] + k0, (char*)&Bs[buf][0] + c * 4096 + wv * 1024);
  };
  auto stage_a32 = [&](int buf, const uint4& r00, const uint4& r01,
                       const uint4& r10, const uint4& r11) {
    union { uint4 u[2]; float4 f[2]; } c0; c0.u[0] = r00; c0.u[1] = r01;
    union { uint4 u[2]; float4 f[2]; } c1; c1.u[0] = r10; c1.u[1] = r11;
    union { short8 s; uint4 u; } o0; o0.s = cvt8(c0.f[0], c0.f[1]);
    union { short8 s; uint4 u; } o1; o1.s = cvt8(c1.f[0], c1.f[1]);
    *(uint4*)((char*)&As[buf][0] + srow * 128 + slotSwz * 16) = o0.u;
    *(uint4*)((char*)&As[buf][0] + (srow + 32) * 128 + slotSwz * 16) = o1.u;
  };

  floatx4 acc[4][NJ] = {};
  stage_lds(0, 0);
  {
    uint4 r00 = *(const uint4*)(a32_0), r01 = *(const uint4*)(a32_0 + 4);
    uint4 r10 = *(const uint4*)(a32_1), r11 = *(const uint4*)(a32_1 + 4);
    stage_a32(0, r00, r01, r10, r11);
  }
  __syncthreads();
#pragma unroll
  for (int k0 = 0; k0 < K; k0 += 64) {
    const int cur = (k0 >> 6) & 1, nxt = cur ^ 1;
    const bool more = (k0 + 64 < K);
    uint4 r00, r01, r10, r11;
    if (more) {
      stage_lds(nxt, k0 + 64);
      r00 = *(const uint4*)(a32_0 + k0 + 64); r01 = *(const uint4*)(a32_0 + k0 + 68);
      r10 = *(const uint4*)(a32_1 + k0 + 64); r11 = *(const uint4*)(a32_1 + k0 + 68);
    }
    short8 af[2][4], bf[2][NJ];
#pragma unroll
    for (int kk2 = 0; kk2 < 2; kk2++) {
      const int slot = ((kk2 << 2) + q) ^ (ml & 7);
#pragma unroll
      for (int i = 0; i < 4; i++)
        af[kk2][i] = *(const short8*)((const char*)&As[cur][0] + (16 * i + ml) * 128 + slot * 16);
#pragma unroll
      for (int j = 0; j < NJ; j++)
        bf[kk2][j] = *(const short8*)((const char*)&Bs[cur][0] + (wn + 16 * j + ml) * 128 + slot * 16);
    }
#pragma unroll
    for (int kk2 = 0; kk2 < 2; kk2++)
#pragma unroll
      for (int i = 0; i < 4; i++)
#pragma unroll
        for (int j = 0; j < NJ; j++)
          acc[i][j] = __builtin_amdgcn_mfma_f32_16x16x32_bf16(af[kk2][i], bf[kk2][j], acc[i][j], 0, 0, 0);
    if (more) {
      stage_a32(nxt, r00, r01, r10, r11);
      __syncthreads();
    }
  }
#pragma unroll
  for (int j = 0; j < NJ; j++) {
    int n = bn + wn + 16 * j + ml;
#pragma unroll
    for (int i = 0; i < 4; i++)
#pragma unroll
      for (int rr = 0; rr < 4; rr++) {
        int m = bm + 16 * i + q * 4 + rr;
        if (m < M) ((ushort*)Cv)[(size_t)m * F + n] = f2b(acc[i][j][rr]);
      }
  }
}

// ---------------- GCN aggregation (unchanged from round 8, verified) ----------------
template<int F>
__global__ __launch_bounds__(256) void agg_kernel(const ushort* __restrict__ H,
                                                  const float* __restrict__ bias,
                                                  const float* __restrict__ dinv,
                                                  const int* __restrict__ rp,
                                                  const unsigned* __restrict__ edg,
                                                  ushort* __restrict__ out, int n) {
  constexpr int VPL = F / 32;
  using hv_t = std::conditional_t<VPL == 8, uint4, uint2>;
  int wid = blockIdx.x * 4 + (threadIdx.x >> 6);
  if (wid >= n) return;
  const int lane = threadIdx.x & 63;
  const int half = lane >> 5;
  const int fo = (lane & 31) * VPL;
  const ushort* Hf = H + fo;

  float acc[VPL];
  if (half == 0) {
    float invd = dinv[wid], ws = invd * invd;
    hv_t h = *(const hv_t*)(Hf + (size_t)wid * F);
    if constexpr (VPL == 8) {
      acc[0] = bias[fo + 0] + ws * blo(h.x); acc[1] = bias[fo + 1] + ws * bhi(h.x);
      acc[2] = bias[fo + 2] + ws * blo(h.y); acc[3] = bias[fo + 3] + ws * bhi(h.y);
      acc[4] = bias[fo + 4] + ws * blo(h.z); acc[5] = bias[fo + 5] + ws * bhi(h.z);
      acc[6] = bias[fo + 6] + ws * blo(h.w); acc[7] = bias[fo + 7] + ws * bhi(h.w);
    } else {
      acc[0] = bias[fo + 0] + ws * blo(h.x); acc[1] = bias[fo + 1] + ws * bhi(h.x);
      acc[2] = bias[fo + 2] + ws * blo(h.y); acc[3] = bias[fo + 3] + ws * bhi(h.y);
    }
  } else {
#pragma unroll
    for (int v = 0; v < VPL; v++) acc[v] = 0.0f;
  }

  auto fmaU = [&](float w, const hv_t& h) {
    if constexpr (VPL == 8) {
      acc[0] += w * blo(h.x); acc[1] += w * bhi(h.x);
      acc[2] += w * blo(h.y); acc[3] += w * bhi(h.y);
      acc[4] += w * blo(h.z); acc[5] += w * bhi(h.z);
      acc[6] += w * blo(h.w); acc[7] += w * bhi(h.w);
    } else {
      acc[0] += w * blo(h.x); acc[1] += w * bhi(h.x);
      acc[2] += w * blo(h.y); acc[3] += w * bhi(h.y);
    }
  };

  const int p1 = rp[wid + 1];
  for (int p = rp[wid] + half; p < p1; p += 8) {
    unsigned e[4]; float w[4];
#pragma unroll
    for (int u = 0; u < 4; u++) {
      int idx = p + 2 * u;
      bool ok = idx < p1;
      e[u] = edg[ok ? idx : (p1 - 1)];
      w[u] = ok ? __half2float(__ushort_as_half((ushort)(e[u] >> 16))) : 0.0f;
    }
    hv_t h[4];
#pragma unroll
    for (int u = 0; u < 4; u++)
      h[u] = *(const hv_t*)(Hf + (size_t)(e[u] & 0xffffu) * F);
#pragma unroll
    for (int u = 0; u < 4; u++) fmaU(w[u], h[u]);
  }

#pragma unroll
  for (int v = 0; v < VPL; v++) acc[v] += __shfl_xor(acc[v], 32, 64);

  if (half == 0) {
    ushort* op = out + (size_t)wid * F + fo;
    if constexpr (VPL == 8) {
      float4 lo = {fmaxf(acc[0], 0.0f), fmaxf(acc[1], 0.0f), fmaxf(acc[2], 0.0f), fmaxf(acc[3], 0.0f)};
      float4 hi = {fmaxf(acc[4], 0.0f), fmaxf(acc[5], 0.0f), fmaxf(acc[6], 0.0f), fmaxf(acc[7], 0.0f)};
      union { short8 s; uint4 u; } o; o.s = cvt8(lo, hi);
      *(uint4*)op = o.u;
    } else {
      union { __hip_bfloat162 h[2]; uint2 u; } o;
      o.h[0] = __float22bfloat162_rn({fmaxf(acc[0], 0.0f), fmaxf(acc[1], 0.0f)});
      o.h[1] = __float22bfloat162_rn({fmaxf(acc[2], 0.0f), fmaxf(acc[3], 0.0f)});
      *(uint2*)op = o.u;
    }
  }
}

// ---------------- launch ----------------

extern "C" void kernel_launch(void* const* d_in, const int* in_sizes, int n_in,
                              void* d_out, int out_size, void* d_ws, size_t ws_size,
                              hipStream_t stream) {
  const float* x  = (const float*)d_in[0];
  const int* ei   = (const int*)d_in[1];
  const float* W1 = (const float*)d_in[2];
  const float* b1 = (const float*)d_in[3];
  const float* W2 = (const float*)d_in[4];
  const float* b2 = (const float*)d_in[5];
  const float* Wc = (const float*)d_in[6];
  const float* bc = (const float*)d_in[7];

  const int N = in_sizes[0] / F_IN;
  const int E = in_sizes[1] / 2;
  const int* e_src = ei;
  const int* e_dst = ei + E;

  // workspace layout (256B aligned). Base ~55.3MB; xb (bf16 x copy) +51.2MB allocated LAST
  // so its absence never shifts other pointers. Fallback: gemm1_fb on f32 x.
  char* ws = (char*)d_ws;
  size_t off = 0;
  auto alloc = [&](size_t bytes) { char* p = ws + off; off += (bytes + 255) & ~(size_t)255; return p; };
  int*      cnt  = (int*)alloc((size_t)N * 4);
  float*    dinv = (float*)alloc((size_t)N * 4);
  int*      rp   = (int*)alloc((size_t)(N + 1) * 4);
  int*      part = (int*)alloc((size_t)1024 * 4);
  unsigned* edg  = (unsigned*)alloc((size_t)E * 4);
  ushort*   w1t  = (ushort*)alloc((size_t)F_HID * F_IN * 2);
  ushort*   w2t  = (ushort*)alloc((size_t)F_MID * F_HID * 2);
  ushort*   wct  = (ushort*)alloc((size_t)F_OUT * F_MID * 2);
  ushort*   bufH = (ushort*)alloc((size_t)N * F_HID * 2);
  ushort*   bufG = (ushort*)alloc((size_t)N * F_HID * 2);
  ushort*   xb   = (ushort*)alloc((size_t)N * F_IN * 2);
  const bool has_xb = (off <= ws_size);
  (void)n_in; (void)out_size;

  int gE = (E + 255) / 256, gW = (N + 3) / 4;
  int gM64 = (N + 63) / 64;
  int nb = (N + 1023) / 1024;

  // CSR + dinv
  hipMemsetAsync(cnt, 0, (size_t)N * 4, stream);
  hist_kernel<<<gE, 256, 0, stream>>>(e_dst, cnt, E);
  scan1_kernel<<<nb, 1024, 0, stream>>>(cnt, rp, part, dinv, N);
  scan2_kernel<<<1, 1024, 0, stream>>>(part, rp, nb, N);
  scan3_kernel<<<nb, 1024, 0, stream>>>(part, rp, N);
  fill_kernel<<<gE, 256, 0, stream>>>(e_src, e_dst, rp, cnt, dinv, edg, E);

  // prep: weight transposes + (if ws allows) x -> bf16, one launch
  {
    int xit = has_xb ? (N * F_IN / 8) : 0;
    int items = xit + F_IN * F_HID + F_HID * F_MID + F_MID * F_OUT;
    prep_kernel<<<(items + 255) / 256, 256, 0, stream>>>(x, xb, xit, W1, w1t, W2, w2t, Wc, wct);
  }

  // layer 1: H = x @ W1
  if (has_xb)
    gemm_ring<512, 128, false, false, true><<<dim3(gM64, 2), 256, 0, stream>>>(xb, w1t, nullptr, bufH, N, F_HID);
  else
    gemm1_fb<<<dim3(gM64, 2), 256, 0, stream>>>(x, w1t, bufH, N, F_HID);
  agg_kernel<F_HID><<<gW, 256, 0, stream>>>(bufH, b1, dinv, rp, edg, bufG, N);

  // layer 2: H2 = h1 @ W2
  gemm_ring<256, 128, false, false, false><<<dim3(gM64, 1), 256, 0, stream>>>(bufG, w2t, nullptr, bufH, N, F_MID);
  agg_kernel<F_MID><<<gW, 256, 0, stream>>>(bufH, b2, dinv, rp, edg, bufG, N);

  // classifier + fused log_softmax
  gemm_ring<128, 64, true, true, false><<<dim3(gM64, 1), 256, 0, stream>>>(bufG, wct, bc, d_out, N, F_OUT);
}

// Round 10
// 411.701 us; speedup vs baseline: 1.0234x; 1.0234x over previous
//
#include <hip/hip_runtime.h>
#include <hip/hip_bf16.h>
#include <hip/hip_fp16.h>
#include <cstdint>
#include <cstddef>
#include <type_traits>

// Problem constants (from reference): N=50000, E=800000, IN=512, HID=256, MID=128, OUT=64
// NOTE: edge packing below assumes N < 65536 (src index fits 16 bits). N=50000 -> ok.
#define F_IN  512
#define F_HID 256
#define F_MID 128
#define F_OUT 64

typedef __attribute__((ext_vector_type(8))) short short8;   // 8 x bf16 (4 VGPRs)
typedef __attribute__((ext_vector_type(4))) float floatx4;  // MFMA accumulator

static __device__ __forceinline__ ushort f2b(float f) {
  union { float f; unsigned u; } v; v.f = f;
  unsigned r = v.u + 0x7fffu + ((v.u >> 16) & 1u);  // round-to-nearest-even
  return (ushort)(r >> 16);
}
static __device__ __forceinline__ float blo(unsigned u) {
  union { unsigned x; float f; } v; v.x = u << 16; return v.f;
}
static __device__ __forceinline__ float bhi(unsigned u) {
  union { unsigned x; float f; } v; v.x = u & 0xffff0000u; return v.f;
}
// 8x f32 -> 8x bf16 via packed v_cvt_pk_bf16_f32 (RNE)
static __device__ __forceinline__ short8 cvt8(float4 lo, float4 hi) {
  union { __hip_bfloat162 h[4]; short8 s; } r;
  r.h[0] = __float22bfloat162_rn({lo.x, lo.y});
  r.h[1] = __float22bfloat162_rn({lo.z, lo.w});
  r.h[2] = __float22bfloat162_rn({hi.x, hi.y});
  r.h[3] = __float22bfloat162_rn({hi.z, hi.w});
  return r.s;
}

// async global->LDS DMA, 16B per lane. LDS dest must be WAVE-UNIFORM base; HW scatters
// lane i to base + i*16. Global src is per-lane. size must be a literal (16).
static __device__ __forceinline__ void gload_lds16(const void* gsrc, void* ldst) {
  __builtin_amdgcn_global_load_lds(
      (const __attribute__((address_space(1))) unsigned int*)gsrc,
      (__attribute__((address_space(3))) unsigned int*)ldst, 16, 0, 0);
}

// counted waitcnt: wait until <=N VMEM outstanding (+ drain LDS queue). NEVER 0 mid-ring.
template<int N> static __device__ __forceinline__ void vm_wait() {
  asm volatile("s_waitcnt vmcnt(%0) lgkmcnt(0)" :: "n"(N) : "memory");
}

// XCD pair swizzle (verified round 8: FETCH halved): col-tile pairs sharing A rows land
// 8 block-ids apart -> same XCD under %8 round-robin. Bijective for (gx, 2) grids.
static __device__ __forceinline__ void pairx_remap(int& bx, int& by) {
  int gx = (int)gridDim.x;
  int id = bx + gx * by;
  int lim = (gx & ~7) * 2;
  if (id < lim) { int u = id >> 4, v = id & 15; bx = u * 8 + (v & 7); by = v >> 3; }
  else { int r = id - lim; bx = (lim >> 1) + (r >> 1); by = r & 1; }
}

// ---------------- CSR build ----------------

__global__ __launch_bounds__(256) void hist_kernel(const int* __restrict__ dst,
                                                   int* __restrict__ cnt, int e) {
  int i = blockIdx.x * 256 + threadIdx.x;
  if (i < e) atomicAdd(&cnt[dst[i]], 1);
}

__global__ __launch_bounds__(1024) void scan1_kernel(int* __restrict__ cnt,
                                                     int* __restrict__ rp,
                                                     int* __restrict__ part,
                                                     float* __restrict__ dinv, int n) {
  __shared__ int buf[1024];
  int tid = threadIdx.x;
  int i = blockIdx.x * 1024 + tid;
  int v = (i < n) ? cnt[i] : 0;
  buf[tid] = v;
  __syncthreads();
  for (int off = 1; off < 1024; off <<= 1) {
    int t = (tid >= off) ? buf[tid - off] : 0;
    __syncthreads();
    buf[tid] += t;
    __syncthreads();
  }
  if (i < n) {
    rp[i] = buf[tid] - v;
    cnt[i] = 0;
    dinv[i] = rsqrtf(1.0f + (float)v);  // deg includes self-loop
  }
  if (tid == 1023) part[blockIdx.x] = buf[1023];
}

__global__ __launch_bounds__(1024) void scan2_kernel(int* __restrict__ part,
                                                     int* __restrict__ rp, int nb, int n) {
  __shared__ int buf[1024];
  int tid = threadIdx.x;
  int v = (tid < nb) ? part[tid] : 0;
  buf[tid] = v;
  __syncthreads();
  for (int off = 1; off < 1024; off <<= 1) {
    int t = (tid >= off) ? buf[tid - off] : 0;
    __syncthreads();
    buf[tid] += t;
    __syncthreads();
  }
  if (tid < nb) part[tid] = buf[tid] - v;
  if (tid == nb - 1) rp[n] = buf[tid];
}

__global__ __launch_bounds__(1024) void scan3_kernel(const int* __restrict__ part,
                                                     int* __restrict__ rp, int n) {
  int b = blockIdx.x;
  int i = b * 1024 + threadIdx.x;
  if (b > 0 && i < n) rp[i] += part[b];
}

// fill CSR adjacency; packs src (low 16 bits) + f16 edge weight (high 16 bits).
__global__ __launch_bounds__(256) void fill_kernel(const int* __restrict__ src,
                                                   const int* __restrict__ dst,
                                                   const int* __restrict__ rp,
                                                   int* __restrict__ cur,
                                                   const float* __restrict__ dinv,
                                                   unsigned* __restrict__ edg, int e) {
  int i = blockIdx.x * 256 + threadIdx.x;
  if (i < e) {
    int s = src[i], d = dst[i];
    int p = rp[d] + atomicAdd(&cur[d], 1);
    float w = dinv[s] * dinv[d];
    edg[p] = ((unsigned)__half_as_ushort(__float2half_rn(w)) << 16) | (unsigned)s;
  }
}

// ---------------- prep: 3 weight transposes in ONE launch (no x conversion -- the round-9
// x->bf16 pass cost ~26us of pure extra traffic and only bought ~7us of gemm1 time) -------
__global__ __launch_bounds__(256) void prep_kernel(const float* __restrict__ W1, ushort* __restrict__ w1t,
                                                   const float* __restrict__ W2, ushort* __restrict__ w2t,
                                                   const float* __restrict__ Wc, ushort* __restrict__ wct) {
  int j = blockIdx.x * 256 + threadIdx.x;
  if (j < F_IN * F_HID) {
    int k = j / F_HID, f = j - k * F_HID;
    w1t[(size_t)f * F_IN + k] = f2b(W1[j]);
  } else if ((j -= F_IN * F_HID) < F_HID * F_MID) {
    int k = j / F_MID, f = j - k * F_MID;
    w2t[(size_t)f * F_HID + k] = f2b(W2[j]);
  } else if ((j -= F_HID * F_MID) < F_MID * F_OUT) {
    int k = j / F_OUT, f = j - k * F_OUT;
    wct[(size_t)f * F_MID + k] = f2b(Wc[j]);
  }
}

// ---------------- gemm1: f32 A, BK=32, 64x128 tile, 2-buffer, PAIRX ----------------
// Round-4 measured base (72us @ FETCH 101MB, occ 39%) + PAIRX (verified: halves FETCH ->
// half the A loads become ~200cyc L2 hits instead of ~900cyc HBM misses). 24KB LDS keeps
// occupancy high -- the latency arithmetic (80cyc MFMA phase vs 900cyc miss) says occupancy
// + L2-conversion are the only levers at this tile size, not prefetch depth (round 8: BK64's
// occupancy loss ate the drain-count gain; round 9: ring works but can't beat the math).
// BK32 LDS rows are 64B -> bank = (row parity, 16B slot); fragment reads spread 8 lanes per
// group = uniform floor, no swizzle needed (round-4 conflict count was staging-incidental).
__global__ __launch_bounds__(256) void gemm1_k512(const float* __restrict__ A,
                                                  const ushort* __restrict__ BT,
                                                  ushort* __restrict__ C, int M, int F) {
  constexpr int K = 512, NT = 128, NJ = 2;
  __shared__ ushort As[2][64 * 32];   // 2 x 4 KB
  __shared__ ushort Bs[2][NT * 32];   // 2 x 8 KB
  const int tid = threadIdx.x, lane = tid & 63, wv = tid >> 6;
  const int q = lane >> 4, ml = lane & 15;

  int bx = blockIdx.x, by = blockIdx.y;
  pairx_remap(bx, by);
  const int bm = bx << 6, bn = by * NT;
  const int wn = wv * (NT / 4);

  const int sr = tid >> 2, sc = (tid & 3) << 3;   // staging row 0..63, col 0/8/16/24
  const int ra = min(bm + sr, M - 1);
  const float* a32 = A + (size_t)ra * K + sc;
  const ushort* bsrc[NJ];
#pragma unroll
  for (int c = 0; c < NJ; c++) {
    int rb = min(bn + 64 * c + sr, F - 1);
    bsrc[c] = BT + (size_t)rb * K + sc;
  }

  auto stage_lds = [&](int buf, int k0) {
#pragma unroll
    for (int c = 0; c < NJ; c++)
      gload_lds16(bsrc[c] + k0, (char*)&Bs[buf][0] + c * 4096 + wv * 1024);
  };
  auto stage_a32 = [&](int buf, const uint4& r0, const uint4& r1) {
    union { uint4 u[2]; float4 f[2]; } cc; cc.u[0] = r0; cc.u[1] = r1;
    union { short8 s; uint4 u; } o; o.s = cvt8(cc.f[0], cc.f[1]);
    *(uint4*)(&As[buf][0] + sr * 32 + sc) = o.u;
  };

  floatx4 acc[4][NJ] = {};

  stage_lds(0, 0);
  {
    uint4 r0 = *(const uint4*)(a32);
    uint4 r1 = *(const uint4*)(a32 + 4);
    stage_a32(0, r0, r1);
  }
  __syncthreads();

#pragma unroll
  for (int k0 = 0; k0 < K; k0 += 32) {
    const int cur = (k0 >> 5) & 1, nxt = cur ^ 1;
    const bool more = (k0 + 32 < K);
    uint4 r0, r1;
    if (more) {
      stage_lds(nxt, k0 + 32);
      r0 = *(const uint4*)(a32 + k0 + 32);
      r1 = *(const uint4*)(a32 + k0 + 36);
    }

    short8 af[4], bf[NJ];
#pragma unroll
    for (int i = 0; i < 4; i++)
      af[i] = *(const short8*)(&As[cur][0] + (16 * i + ml) * 32 + q * 8);
#pragma unroll
    for (int j = 0; j < NJ; j++)
      bf[j] = *(const short8*)(&Bs[cur][0] + (wn + 16 * j + ml) * 32 + q * 8);
#pragma unroll
    for (int i = 0; i < 4; i++)
#pragma unroll
      for (int j = 0; j < NJ; j++)
        acc[i][j] = __builtin_amdgcn_mfma_f32_16x16x32_bf16(af[i], bf[j], acc[i][j], 0, 0, 0);

    if (more) {
      stage_a32(nxt, r0, r1);
      __syncthreads();
    }
  }

  // epilogue: C/D col = lane&15, row = quad*4 + reg [m89 verified]
#pragma unroll
  for (int j = 0; j < NJ; j++) {
    int n = bn + wn + 16 * j + ml;
#pragma unroll
    for (int i = 0; i < 4; i++)
#pragma unroll
      for (int rr = 0; rr < 4; rr++) {
        int m = bm + 16 * i + q * 4 + rr;
        if (m < M) C[(size_t)m * F + n] = f2b(acc[i][j][rr]);
      }
  }
}

// ---------------- gemm2/3: 3-buffer ring, depth-2 prefetch, counted vmcnt (round-9 run) ----
// A bf16 [M][K], BT bf16 [F][K]. Per iter: s_waitcnt vmcnt(L) (L = successor tile's in-flight
// loads, never 0) + raw s_barrier + sched_barrier(0) (rule 18). BK=64 128B rows -> XOR
// swizzle (verified round 8: SQ_LDS_BANK_CONFLICT == 0). LSM fuses log_softmax epilogue.
template<int K, int NT, bool OUT_F32, bool LSM>
__global__ __launch_bounds__(256) void gemm_ring(const ushort* __restrict__ A16,
                                                 const ushort* __restrict__ BT,
                                                 const float* __restrict__ bias,
                                                 void* __restrict__ Cv,
                                                 int M, int F) {
  constexpr int NK   = K / 64;
  constexpr int NJ   = NT / 64;
  constexpr int NCHB = NT / 32;
  constexpr int L    = NCHB + 2;      // DMA per wave per tile (B chunks + 2 A chunks)
  __shared__ ushort As[3][64 * 64];
  __shared__ ushort Bs[3][NT * 64];
  const int tid = threadIdx.x, lane = tid & 63, wv = tid >> 6;
  const int q = lane >> 4, ml = lane & 15;

  const int bm = blockIdx.x << 6, bn = blockIdx.y * NT;
  const int wn = wv * (NT / 4);

  const int srow = tid >> 3;
  const int scS = ((tid & 7) ^ (srow & 7)) << 3;  // pre-swizzled source col

  const ushort* a0 = A16 + (size_t)min(bm + srow, M - 1) * K + scS;
  const ushort* a1 = A16 + (size_t)min(bm + 32 + srow, M - 1) * K + scS;
  const ushort* bsrc[NCHB];
#pragma unroll
  for (int c = 0; c < NCHB; c++) {
    int rb = min(bn + 32 * c + srow, F - 1);
    bsrc[c] = BT + (size_t)rb * K + scS;
  }

  auto stage = [&](int buf, int k0) {
#pragma unroll
    for (int c = 0; c < NCHB; c++)
      gload_lds16(bsrc[c] + k0, (char*)&Bs[buf][0] + c * 4096 + wv * 1024);
    gload_lds16(a0 + k0, (char*)&As[buf][0] + wv * 1024);
    gload_lds16(a1 + k0, (char*)&As[buf][0] + 4096 + wv * 1024);
  };

  floatx4 acc[4][NJ] = {};

  stage(0, 0);
  if (NK > 1) stage(1, 64);

#pragma unroll
  for (int k = 0; k < NK; k++) {
    if (k + 1 < NK) vm_wait<L>(); else vm_wait<0>();
    __builtin_amdgcn_s_barrier();
    __builtin_amdgcn_sched_barrier(0);

    const int cur = k % 3;
    short8 af[2][4], bf[2][NJ];
#pragma unroll
    for (int kk2 = 0; kk2 < 2; kk2++) {
      const int slot = ((kk2 << 2) + q) ^ (ml & 7);
#pragma unroll
      for (int i = 0; i < 4; i++)
        af[kk2][i] = *(const short8*)((const char*)&As[cur][0] + (16 * i + ml) * 128 + slot * 16);
#pragma unroll
      for (int j = 0; j < NJ; j++)
        bf[kk2][j] = *(const short8*)((const char*)&Bs[cur][0] + (wn + 16 * j + ml) * 128 + slot * 16);
    }
#pragma unroll
    for (int kk2 = 0; kk2 < 2; kk2++)
#pragma unroll
      for (int i = 0; i < 4; i++)
#pragma unroll
        for (int j = 0; j < NJ; j++)
          acc[i][j] = __builtin_amdgcn_mfma_f32_16x16x32_bf16(af[kk2][i], bf[kk2][j], acc[i][j], 0, 0, 0);

    if (k + 2 < NK) stage((k + 2) % 3, (k + 2) * 64);
  }

  if constexpr (LSM) {
    __shared__ float lsm[64][65];
    __syncthreads();
#pragma unroll
    for (int i = 0; i < 4; i++)
#pragma unroll
      for (int rr = 0; rr < 4; rr++)
        lsm[16 * i + q * 4 + rr][wn + ml] = acc[i][0][rr] + bias[wn + ml];
    __syncthreads();
    for (int t = 0; t < 16; ++t) {
      int r = (wv << 4) + t;
      float l = lsm[r][lane];
      float mx = l;
#pragma unroll
      for (int off = 32; off; off >>= 1) mx = fmaxf(mx, __shfl_xor(mx, off, 64));
      float e = __expf(l - mx);
#pragma unroll
      for (int off = 32; off; off >>= 1) e += __shfl_xor(e, off, 64);
      int m = bm + r;
      if (m < M) ((float*)Cv)[(size_t)m * 64 + lane] = (l - mx) - __logf(e);
    }
  } else {
#pragma unroll
    for (int j = 0; j < NJ; j++) {
      int n = bn + wn + 16 * j + ml;
      float bv = bias ? bias[n] : 0.0f;
#pragma unroll
      for (int i = 0; i < 4; i++) {
#pragma unroll
        for (int rr = 0; rr < 4; rr++) {
          int m = bm + 16 * i + q * 4 + rr;
          if (m < M) {
            float val = acc[i][j][rr] + bv;
            if (OUT_F32) ((float*)Cv)[(size_t)m * F + n] = val;
            else         ((ushort*)Cv)[(size_t)m * F + n] = f2b(val);
          }
        }
      }
    }
  }
}

// ---------------- GCN aggregation: depth-8 clamped edge pipeline ----------------
// Two 32-lane halves per wave; mean half-degree = 8 -> typical node now completes in ONE
// 8-deep load batch (was two 4-deep). OOB slots: clamped valid index (same address ->
// L1-hit), weight 0. Halves merged via one __shfl_xor(32) per acc; half 0 stores.
template<int F>
__global__ __launch_bounds__(256) void agg_kernel(const ushort* __restrict__ H,
                                                  const float* __restrict__ bias,
                                                  const float* __restrict__ dinv,
                                                  const int* __restrict__ rp,
                                                  const unsigned* __restrict__ edg,
                                                  ushort* __restrict__ out, int n) {
  constexpr int VPL = F / 32;
  using hv_t = std::conditional_t<VPL == 8, uint4, uint2>;
  int wid = blockIdx.x * 4 + (threadIdx.x >> 6);
  if (wid >= n) return;
  const int lane = threadIdx.x & 63;
  const int half = lane >> 5;
  const int fo = (lane & 31) * VPL;
  const ushort* Hf = H + fo;

  float acc[VPL];
  if (half == 0) {
    float invd = dinv[wid], ws = invd * invd;
    hv_t h = *(const hv_t*)(Hf + (size_t)wid * F);
    if constexpr (VPL == 8) {
      acc[0] = bias[fo + 0] + ws * blo(h.x); acc[1] = bias[fo + 1] + ws * bhi(h.x);
      acc[2] = bias[fo + 2] + ws * blo(h.y); acc[3] = bias[fo + 3] + ws * bhi(h.y);
      acc[4] = bias[fo + 4] + ws * blo(h.z); acc[5] = bias[fo + 5] + ws * bhi(h.z);
      acc[6] = bias[fo + 6] + ws * blo(h.w); acc[7] = bias[fo + 7] + ws * bhi(h.w);
    } else {
      acc[0] = bias[fo + 0] + ws * blo(h.x); acc[1] = bias[fo + 1] + ws * bhi(h.x);
      acc[2] = bias[fo + 2] + ws * blo(h.y); acc[3] = bias[fo + 3] + ws * bhi(h.y);
    }
  } else {
#pragma unroll
    for (int v = 0; v < VPL; v++) acc[v] = 0.0f;
  }

  auto fmaU = [&](float w, const hv_t& h) {
    if constexpr (VPL == 8) {
      acc[0] += w * blo(h.x); acc[1] += w * bhi(h.x);
      acc[2] += w * blo(h.y); acc[3] += w * bhi(h.y);
      acc[4] += w * blo(h.z); acc[5] += w * bhi(h.z);
      acc[6] += w * blo(h.w); acc[7] += w * bhi(h.w);
    } else {
      acc[0] += w * blo(h.x); acc[1] += w * bhi(h.x);
      acc[2] += w * blo(h.y); acc[3] += w * bhi(h.y);
    }
  };

  const int p1 = rp[wid + 1];
  for (int p = rp[wid] + half; p < p1; p += 16) {
    unsigned e[8]; float w[8];
#pragma unroll
    for (int u = 0; u < 8; u++) {
      int idx = p + 2 * u;
      bool ok = idx < p1;
      e[u] = edg[ok ? idx : (p1 - 1)];    // p1 >= 1 whenever the loop runs
      w[u] = ok ? __half2float(__ushort_as_half((ushort)(e[u] >> 16))) : 0.0f;
    }
    hv_t h[8];
#pragma unroll
    for (int u = 0; u < 8; u++)
      h[u] = *(const hv_t*)(Hf + (size_t)(e[u] & 0xffffu) * F);
#pragma unroll
    for (int u = 0; u < 8; u++) fmaU(w[u], h[u]);
  }

#pragma unroll
  for (int v = 0; v < VPL; v++) acc[v] += __shfl_xor(acc[v], 32, 64);

  if (half == 0) {
    ushort* op = out + (size_t)wid * F + fo;
    if constexpr (VPL == 8) {
      float4 lo = {fmaxf(acc[0], 0.0f), fmaxf(acc[1], 0.0f), fmaxf(acc[2], 0.0f), fmaxf(acc[3], 0.0f)};
      float4 hi = {fmaxf(acc[4], 0.0f), fmaxf(acc[5], 0.0f), fmaxf(acc[6], 0.0f), fmaxf(acc[7], 0.0f)};
      union { short8 s; uint4 u; } o; o.s = cvt8(lo, hi);
      *(uint4*)op = o.u;
    } else {
      union { __hip_bfloat162 h[2]; uint2 u; } o;
      o.h[0] = __float22bfloat162_rn({fmaxf(acc[0], 0.0f), fmaxf(acc[1], 0.0f)});
      o.h[1] = __float22bfloat162_rn({fmaxf(acc[2], 0.0f), fmaxf(acc[3], 0.0f)});
      *(uint2*)op = o.u;
    }
  }
}

// ---------------- launch ----------------

extern "C" void kernel_launch(void* const* d_in, const int* in_sizes, int n_in,
                              void* d_out, int out_size, void* d_ws, size_t ws_size,
                              hipStream_t stream) {
  const float* x  = (const float*)d_in[0];
  const int* ei   = (const int*)d_in[1];
  const float* W1 = (const float*)d_in[2];
  const float* b1 = (const float*)d_in[3];
  const float* W2 = (const float*)d_in[4];
  const float* b2 = (const float*)d_in[5];
  const float* Wc = (const float*)d_in[6];
  const float* bc = (const float*)d_in[7];

  const int N = in_sizes[0] / F_IN;
  const int E = in_sizes[1] / 2;
  const int* e_src = ei;
  const int* e_dst = ei + E;

  // workspace layout (256B aligned slices); total ~55.3 MB (xb dropped)
  char* ws = (char*)d_ws;
  size_t off = 0;
  auto alloc = [&](size_t bytes) { char* p = ws + off; off += (bytes + 255) & ~(size_t)255; return p; };
  int*      cnt  = (int*)alloc((size_t)N * 4);
  float*    dinv = (float*)alloc((size_t)N * 4);
  int*      rp   = (int*)alloc((size_t)(N + 1) * 4);
  int*      part = (int*)alloc((size_t)1024 * 4);
  unsigned* edg  = (unsigned*)alloc((size_t)E * 4);
  ushort*   w1t  = (ushort*)alloc((size_t)F_HID * F_IN * 2);
  ushort*   w2t  = (ushort*)alloc((size_t)F_MID * F_HID * 2);
  ushort*   wct  = (ushort*)alloc((size_t)F_OUT * F_MID * 2);
  ushort*   bufH = (ushort*)alloc((size_t)N * F_HID * 2);
  ushort*   bufG = (ushort*)alloc((size_t)N * F_HID * 2);
  (void)ws_size; (void)n_in; (void)out_size;

  int gE = (E + 255) / 256, gW = (N + 3) / 4;
  int gM64 = (N + 63) / 64;
  int nb = (N + 1023) / 1024;

  // CSR + dinv
  hipMemsetAsync(cnt, 0, (size_t)N * 4, stream);
  hist_kernel<<<gE, 256, 0, stream>>>(e_dst, cnt, E);
  scan1_kernel<<<nb, 1024, 0, stream>>>(cnt, rp, part, dinv, N);
  scan2_kernel<<<1, 1024, 0, stream>>>(part, rp, nb, N);
  scan3_kernel<<<nb, 1024, 0, stream>>>(part, rp, N);
  fill_kernel<<<gE, 256, 0, stream>>>(e_src, e_dst, rp, cnt, dinv, edg, E);

  // prep: 3 weight transposes, one launch
  {
    int items = F_IN * F_HID + F_HID * F_MID + F_MID * F_OUT;
    prep_kernel<<<(items + 255) / 256, 256, 0, stream>>>(W1, w1t, W2, w2t, Wc, wct);
  }

  // layer 1: H = x @ W1 (f32 A, BK32 2-buffer, PAIRX, 24KB LDS)
  gemm1_k512<<<dim3(gM64, 2), 256, 0, stream>>>(x, w1t, bufH, N, F_HID);
  agg_kernel<F_HID><<<gW, 256, 0, stream>>>(bufH, b1, dinv, rp, edg, bufG, N);

  // layer 2: H2 = h1 @ W2 (ring)
  gemm_ring<256, 128, false, false><<<dim3(gM64, 1), 256, 0, stream>>>(bufG, w2t, nullptr, bufH, N, F_MID);
  agg_kernel<F_MID><<<gW, 256, 0, stream>>>(bufH, b2, dinv, rp, edg, bufG, N);

  // classifier + fused log_softmax (ring)
  gemm_ring<128, 64, true, true><<<dim3(gM64, 1), 256, 0, stream>>>(bufG, wct, bc, d_out, N, F_OUT);
}